// Round 12
// baseline (438.754 us; speedup 1.0000x reference)
//
#include <hip/hip_runtime.h>
#include <hip/hip_bf16.h>

#define NN 50000
#define NE 1600000
#define FEAT 128
#define NG 128
#define NC 10

#define BUCK 256
#define NBUCK ((NN + BUCK - 1) / BUCK)   // 196
#define EPB 8192
#define NBLK1 ((NE + EPB - 1) / EPB)     // 196

typedef unsigned int u32x4 __attribute__((ext_vector_type(4)));
typedef short bf16x8 __attribute__((ext_vector_type(8)));
typedef float f32x4 __attribute__((ext_vector_type(4)));

// ---------------- bf16 helpers (manual, RNE) ----------------
__device__ __forceinline__ float bflo(unsigned u) { return __uint_as_float(u << 16); }
__device__ __forceinline__ float bfhi(unsigned u) { return __uint_as_float(u & 0xffff0000u); }
__device__ __forceinline__ float bfs(unsigned u) { return __uint_as_float(u << 16); }
__device__ __forceinline__ unsigned packbf(float a, float b) {
    unsigned ua = __float_as_uint(a), ub = __float_as_uint(b);
    ua += 0x7fffu + ((ua >> 16) & 1u);
    ub += 0x7fffu + ((ub >> 16) & 1u);
    return (ua >> 16) | (ub & 0xffff0000u);
}
__device__ __forceinline__ unsigned short bf1(float a) {
    unsigned ua = __float_as_uint(a);
    ua += 0x7fffu + ((ua >> 16) & 1u);
    return (unsigned short)(ua >> 16);
}

// ---------------- p1a: per-block bucket histogram (LDS atomics only) ----------------
__global__ __launch_bounds__(256) void k_hist(const int* __restrict__ col,
                                              int* __restrict__ blockHist) {
    __shared__ int h[BUCK];
    h[threadIdx.x] = 0;
    __syncthreads();
    const int base = blockIdx.x * EPB;
    const int end = min(base + EPB, NE);
    for (int e = base + threadIdx.x; e < end; e += 256)
        atomicAdd(&h[col[e] >> 8], 1);
    __syncthreads();
    blockHist[threadIdx.x * NBLK1 + blockIdx.x] = h[threadIdx.x];
}

// ---------------- p1b: per-bucket block-prefix + bucket-total scan ----------------
__global__ __launch_bounds__(256) void k_scanbk(int* __restrict__ blockHist,
                                                int* __restrict__ bucketOff,
                                                int* __restrict__ offsets) {
    __shared__ int tmp[256];
    const int t = threadIdx.x;
    int sum = 0;
    if (t < NBUCK) {
        for (int blk = 0; blk < NBLK1; ++blk) {
            int v = blockHist[t * NBLK1 + blk];
            blockHist[t * NBLK1 + blk] = sum; // within-bucket exclusive prefix
            sum += v;
        }
    }
    tmp[t] = sum;
    __syncthreads();
    for (int d = 1; d < 256; d <<= 1) {
        int u = (t >= d) ? tmp[t - d] : 0;
        __syncthreads();
        tmp[t] += u;
        __syncthreads();
    }
    const int excl = tmp[t] - sum;
    if (t < NBUCK) {
        bucketOff[t] = excl;
        for (int blk = 0; blk < NBLK1; ++blk)
            blockHist[t * NBLK1 + blk] += excl;
    }
    if (t == 0) { bucketOff[NBUCK] = NE; offsets[NN] = NE; }
}

// ---------------- p1c: scatter packed records into bucket-grouped order ----------------
// record: lo32 = row(16b) | c_local(8b)<<16 ; hi32 = ew bits (f32)
__global__ __launch_bounds__(256) void k_scatter(const int* __restrict__ row,
                                                 const int* __restrict__ col,
                                                 const float* __restrict__ ew,
                                                 const int* __restrict__ blockHist,
                                                 long long* __restrict__ binned) {
    __shared__ int cur[BUCK];
    cur[threadIdx.x] = blockHist[threadIdx.x * NBLK1 + blockIdx.x];
    __syncthreads();
    const int base = blockIdx.x * EPB;
    const int end = min(base + EPB, NE);
    for (int e = base + threadIdx.x; e < end; e += 256) {
        int c = col[e];
        int pos = atomicAdd(&cur[c >> 8], 1);
        long long v = (long long)(unsigned)(row[e] | ((c & 255) << 16)) |
                      ((long long)__float_as_int(ew[e]) << 32);
        binned[pos] = v;
    }
}

// ---------------- p2: per-bucket CSR finalize + offsets + dinv (LDS atomics) ----------
// csr entry (4B): row(16b) | bf16(ew)<<16.  dinv uses full-f32 ew sums.
__global__ __launch_bounds__(256) void k_csr(const long long* __restrict__ binned,
                                             const int* __restrict__ bucketOff,
                                             unsigned int* __restrict__ csr,
                                             int* __restrict__ offsets,
                                             float* __restrict__ dinv) {
    __shared__ int cnt[BUCK], off[BUCK], cnt2[BUCK];
    __shared__ float wsum[BUCK];
    const int b = blockIdx.x;
    const int t = threadIdx.x;
    cnt[t] = 0; cnt2[t] = 0; wsum[t] = 0.f;
    __syncthreads();
    const int s = bucketOff[b], e = bucketOff[b + 1];
    for (int i = s + t; i < e; i += 256) {
        int lo = (int)binned[i];
        atomicAdd(&cnt[(lo >> 16) & 255], 1);
    }
    __syncthreads();
    // exclusive scan cnt -> off
    int v0 = cnt[t];
    off[t] = v0;
    __syncthreads();
    for (int d = 1; d < 256; d <<= 1) {
        int u = (t >= d) ? off[t - d] : 0;
        __syncthreads();
        off[t] += u;
        __syncthreads();
    }
    int myoff = off[t] - v0;
    __syncthreads();
    off[t] = myoff;
    __syncthreads();
    for (int i = s + t; i < e; i += 256) {
        long long v = binned[i];
        int lo = (int)v;
        int c = (lo >> 16) & 255;
        float w = __int_as_float((int)(v >> 32));
        int r = atomicAdd(&cnt2[c], 1);
        atomicAdd(&wsum[c], w);
        csr[s + off[c] + r] = (unsigned)(lo & 0xFFFF) | ((unsigned)bf1(w) << 16);
    }
    __syncthreads();
    const int node = b * BUCK + t;
    if (node < NN) {
        offsets[node] = s + off[t];
        dinv[node] = rsqrtf(wsum[t] + 1.0f); // +1 = self-loop weight
    }
}

// ---------------- W[k][n] f32 -> Wt[n][k] bf16 ----------------
__global__ void k_prepW(const float* __restrict__ W, unsigned short* __restrict__ Wt) {
    int idx = blockIdx.x * 256 + threadIdx.x; // 16384 threads
    int k = idx >> 7, n = idx & 127;
    Wt[n * 128 + k] = bf1(W[idx]);
}

// ---------------- MFMA GEMM: C_bf16 = dinv[row] * (A[NN x 128] @ W[128 x 128]) ----
template <typename TIN>
__global__ __launch_bounds__(256) void k_gemm_mfma(const TIN* __restrict__ A,
                                                   const unsigned short* __restrict__ Wt,
                                                   const float* __restrict__ dinv,
                                                   unsigned short* __restrict__ C) {
    const int t = threadIdx.x;
    const int wid = t >> 6;
    const int lane = t & 63;
    const int row0 = blockIdx.x * 64 + wid * 16;
    const int l15 = lane & 15;
    const int kg = lane >> 4; // 0..3

    int arow = row0 + l15;
    if (arow >= NN) arow = NN - 1; // clamp; stores guarded
    bf16x8 a[4];
    if constexpr (sizeof(TIN) == 2) {
        const unsigned short* ap = (const unsigned short*)A + (size_t)arow * 128 + kg * 8;
#pragma unroll
        for (int ks = 0; ks < 4; ++ks)
            a[ks] = *(const bf16x8*)(ap + ks * 32);
    } else {
        const float* ap = (const float*)A + (size_t)arow * 128 + kg * 8;
#pragma unroll
        for (int ks = 0; ks < 4; ++ks) {
            float4 v0 = *(const float4*)(ap + ks * 32);
            float4 v1 = *(const float4*)(ap + ks * 32 + 4);
            u32x4 o;
            o.x = packbf(v0.x, v0.y); o.y = packbf(v0.z, v0.w);
            o.z = packbf(v1.x, v1.y); o.w = packbf(v1.z, v1.w);
            a[ks] = __builtin_bit_cast(bf16x8, o);
        }
    }

    f32x4 acc[8];
#pragma unroll
    for (int ct = 0; ct < 8; ++ct) acc[ct] = (f32x4){0.f, 0.f, 0.f, 0.f};

#pragma unroll
    for (int ct = 0; ct < 8; ++ct) {
        const unsigned short* bp = Wt + (size_t)(ct * 16 + l15) * 128 + kg * 8;
#pragma unroll
        for (int ks = 0; ks < 4; ++ks) {
            bf16x8 b = *(const bf16x8*)(bp + ks * 32);
            acc[ct] = __builtin_amdgcn_mfma_f32_16x16x32_bf16(a[ks], b, acc[ct], 0, 0, 0);
        }
    }

    const int drow0 = row0 + kg * 4;
    float di[4];
#pragma unroll
    for (int r = 0; r < 4; ++r)
        di[r] = (drow0 + r < NN) ? dinv[drow0 + r] : 0.f;
#pragma unroll
    for (int ct = 0; ct < 8; ++ct) {
#pragma unroll
        for (int r = 0; r < 4; ++r) {
            int grow = drow0 + r;
            if (grow < NN)
                C[(size_t)grow * 128 + ct * 16 + l15] = bf1(acc[ct][r] * di[r]);
        }
    }
}

// ---------------- pull aggregation: quarter-wave, 32 edges in flight ----------
// csr entry: row(16) | bf16(ew)<<16. 16 lanes = one 256B row; 4 edge groups;
// unroll 8 -> 8 CSR loads + 8 gather insts outstanding per wave.
__global__ __launch_bounds__(256) void k_agg(const unsigned short* __restrict__ hs,
                                             const int* __restrict__ offsets,
                                             const unsigned int* __restrict__ csr,
                                             const float* __restrict__ dinv,
                                             const float* __restrict__ bias,
                                             unsigned short* __restrict__ outb) {
    const int node = blockIdx.x * 4 + (threadIdx.x >> 6);
    if (node >= NN) return;
    const int lane = threadIdx.x & 63;
    const int qg = lane >> 4;   // quarter-group: which edge of 4
    const int fl = lane & 15;   // feature lane: owns feats [fl*8, fl*8+8)

    const int start = offsets[node];
    const int cnt = offsets[node + 1] - start;
    const unsigned int* ep = csr + start;
    const uint4* hb = (const uint4*)hs;

    float a0 = 0.f, a1 = 0.f, a2 = 0.f, a3 = 0.f;
    float a4 = 0.f, a5 = 0.f, a6 = 0.f, a7 = 0.f;

    auto fma8 = [&](uint4 v, float w) {
        a0 += bflo(v.x) * w; a1 += bfhi(v.x) * w;
        a2 += bflo(v.y) * w; a3 += bfhi(v.y) * w;
        a4 += bflo(v.z) * w; a5 += bfhi(v.z) * w;
        a6 += bflo(v.w) * w; a7 += bfhi(v.w) * w;
    };

    const int n32 = cnt >> 5;
    for (int i = 0; i < n32; ++i) {
        const int base = i * 32 + qg;
        unsigned e0 = __builtin_nontemporal_load(ep + base);
        unsigned e1 = __builtin_nontemporal_load(ep + base + 4);
        unsigned e2 = __builtin_nontemporal_load(ep + base + 8);
        unsigned e3 = __builtin_nontemporal_load(ep + base + 12);
        unsigned e4 = __builtin_nontemporal_load(ep + base + 16);
        unsigned e5 = __builtin_nontemporal_load(ep + base + 20);
        unsigned e6 = __builtin_nontemporal_load(ep + base + 24);
        unsigned e7 = __builtin_nontemporal_load(ep + base + 28);
        uint4 v0 = hb[(size_t)(e0 & 0xFFFFu) * 16 + fl];
        uint4 v1 = hb[(size_t)(e1 & 0xFFFFu) * 16 + fl];
        uint4 v2 = hb[(size_t)(e2 & 0xFFFFu) * 16 + fl];
        uint4 v3 = hb[(size_t)(e3 & 0xFFFFu) * 16 + fl];
        uint4 v4 = hb[(size_t)(e4 & 0xFFFFu) * 16 + fl];
        uint4 v5 = hb[(size_t)(e5 & 0xFFFFu) * 16 + fl];
        uint4 v6 = hb[(size_t)(e6 & 0xFFFFu) * 16 + fl];
        uint4 v7 = hb[(size_t)(e7 & 0xFFFFu) * 16 + fl];
        fma8(v0, bfs(e0 >> 16));
        fma8(v1, bfs(e1 >> 16));
        fma8(v2, bfs(e2 >> 16));
        fma8(v3, bfs(e3 >> 16));
        fma8(v4, bfs(e4 >> 16));
        fma8(v5, bfs(e5 >> 16));
        fma8(v6, bfs(e6 >> 16));
        fma8(v7, bfs(e7 >> 16));
    }
    for (int jj = n32 * 32; jj < cnt; jj += 4) {
        int idx = jj + qg;
        bool valid = idx < cnt;
        unsigned e = __builtin_nontemporal_load(ep + (valid ? idx : cnt - 1));
        float w = valid ? bfs(e >> 16) : 0.f;
        uint4 v = hb[(size_t)(e & 0xFFFFu) * 16 + fl];
        fma8(v, w);
    }

    a0 += __shfl_xor(a0, 16); a0 += __shfl_xor(a0, 32);
    a1 += __shfl_xor(a1, 16); a1 += __shfl_xor(a1, 32);
    a2 += __shfl_xor(a2, 16); a2 += __shfl_xor(a2, 32);
    a3 += __shfl_xor(a3, 16); a3 += __shfl_xor(a3, 32);
    a4 += __shfl_xor(a4, 16); a4 += __shfl_xor(a4, 32);
    a5 += __shfl_xor(a5, 16); a5 += __shfl_xor(a5, 32);
    a6 += __shfl_xor(a6, 16); a6 += __shfl_xor(a6, 32);
    a7 += __shfl_xor(a7, 16); a7 += __shfl_xor(a7, 32);

    if (qg == 0) {
        uint4 sv = hb[(size_t)node * 16 + fl];
        fma8(sv, 1.0f);                        // self-loop term: + hs[node]
        float di = dinv[node];
        float4 b0 = *(const float4*)(bias + fl * 8);
        float4 b1 = *(const float4*)(bias + fl * 8 + 4);
        a0 = fmaxf(di * a0 + b0.x, 0.f);
        a1 = fmaxf(di * a1 + b0.y, 0.f);
        a2 = fmaxf(di * a2 + b0.z, 0.f);
        a3 = fmaxf(di * a3 + b0.w, 0.f);
        a4 = fmaxf(di * a4 + b1.x, 0.f);
        a5 = fmaxf(di * a5 + b1.y, 0.f);
        a6 = fmaxf(di * a6 + b1.z, 0.f);
        a7 = fmaxf(di * a7 + b1.w, 0.f);
        u32x4 o;
        o.x = packbf(a0, a1); o.y = packbf(a2, a3);
        o.z = packbf(a4, a5); o.w = packbf(a6, a7);
        __builtin_nontemporal_store(o, (u32x4*)(outb + (size_t)node * 128 + fl * 8));
    }
}

// ---------------- segmented pooling (batch sorted): one block per graph --------------
__global__ __launch_bounds__(256) void k_pool(const unsigned short* __restrict__ h3,
                                              const int* __restrict__ batch,
                                              float* __restrict__ pooled) {
    __shared__ float sm[256];
    const int g = blockIdx.x;
    const int f = threadIdx.x & 127;
    const int half = threadIdx.x >> 7;
    int lo = 0, hi = NN;
    while (lo < hi) { int m = (lo + hi) >> 1; if (batch[m] < g) lo = m + 1; else hi = m; }
    int s0 = lo;
    hi = NN;
    while (lo < hi) { int m = (lo + hi) >> 1; if (batch[m] < g + 1) lo = m + 1; else hi = m; }
    int e0 = lo;

    float s = 0.f;
    int n = s0 + half;
    for (; n + 8 <= e0; n += 8) {
        s += bfs((unsigned)h3[(size_t)n * 128 + f]);
        s += bfs((unsigned)h3[(size_t)(n + 2) * 128 + f]);
        s += bfs((unsigned)h3[(size_t)(n + 4) * 128 + f]);
        s += bfs((unsigned)h3[(size_t)(n + 6) * 128 + f]);
    }
    for (; n < e0; n += 2) s += bfs((unsigned)h3[(size_t)n * 128 + f]);

    sm[threadIdx.x] = s;
    __syncthreads();
    if (half == 0) pooled[(size_t)g * 128 + f] = sm[threadIdx.x] + sm[threadIdx.x + 128];
}

// ---------------- FC + log_softmax: one wave per graph ----------------
__global__ __launch_bounds__(64) void k_fc(const float* __restrict__ pooled,
                                           const float* __restrict__ Wfc,
                                           const float* __restrict__ bfc,
                                           float* __restrict__ out) {
    const int g = blockIdx.x;
    const int lane = threadIdx.x;
    float p0 = pooled[(size_t)g * 128 + lane];
    float p1 = pooled[(size_t)g * 128 + 64 + lane];
    float logits[NC];
#pragma unroll
    for (int c = 0; c < NC; ++c) {
        float v = p0 * Wfc[lane * NC + c] + p1 * Wfc[(64 + lane) * NC + c];
#pragma unroll
        for (int off = 32; off > 0; off >>= 1) v += __shfl_down(v, off);
        logits[c] = v;
    }
    if (lane == 0) {
        float mx = -1e30f;
#pragma unroll
        for (int c = 0; c < NC; ++c) { logits[c] += bfc[c]; mx = fmaxf(mx, logits[c]); }
        float s = 0.f;
#pragma unroll
        for (int c = 0; c < NC; ++c) s += expf(logits[c] - mx);
        float lse = mx + logf(s);
#pragma unroll
        for (int c = 0; c < NC; ++c) out[(size_t)g * NC + c] = logits[c] - lse;
    }
}

extern "C" void kernel_launch(void* const* d_in, const int* in_sizes, int n_in,
                              void* d_out, int out_size, void* d_ws, size_t ws_size,
                              hipStream_t stream) {
    const float* x         = (const float*)d_in[0];
    const int*   edge_index= (const int*)d_in[1];
    const int*   batch     = (const int*)d_in[2];
    const float* edge_mask = (const float*)d_in[3];
    const float* W1        = (const float*)d_in[4];
    const float* b1        = (const float*)d_in[5];
    const float* W2        = (const float*)d_in[6];
    const float* b2        = (const float*)d_in[7];
    const float* Wfc       = (const float*)d_in[8];
    const float* bfc       = (const float*)d_in[9];
    float* out = (float*)d_out;

    const int* row = edge_index;        // edge_index[0]
    const int* col = edge_index + NE;   // edge_index[1]

    char* ws = (char*)d_ws;
    size_t off = 0;
    auto alloc = [&](size_t bytes) -> void* {
        off = (off + 255) & ~(size_t)255;
        void* p = ws + off;
        off += bytes;
        return p;
    };
    int*   blockHist= (int*)  alloc((size_t)256 * NBLK1 * 4);
    int*   bucketOff= (int*)  alloc((size_t)(NBUCK + 1) * 4);
    int*   offsets  = (int*)  alloc((size_t)(NN + 1) * 4);
    float* dinv     = (float*)alloc((size_t)NN * 4);
    long long* binned = (long long*)alloc((size_t)NE * 8);
    unsigned int* csr = (unsigned int*)alloc((size_t)NE * 4);
    unsigned short* hs1 = (unsigned short*)alloc((size_t)NN * FEAT * 2); // scaled bf16
    unsigned short* h2  = (unsigned short*)alloc((size_t)NN * FEAT * 2);
    unsigned short* h3  = (unsigned short*)alloc((size_t)NN * FEAT * 2);
    unsigned short* Wt1 = (unsigned short*)alloc((size_t)FEAT * FEAT * 2);
    unsigned short* Wt2 = (unsigned short*)alloc((size_t)FEAT * FEAT * 2);
    float* pooled   = (float*)alloc((size_t)NG * FEAT * 4);

    // ---- CSR build: zero global atomics ----
    k_hist<<<NBLK1, 256, 0, stream>>>(col, blockHist);
    k_scanbk<<<1, 256, 0, stream>>>(blockHist, bucketOff, offsets);
    k_scatter<<<NBLK1, 256, 0, stream>>>(row, col, edge_mask, blockHist, binned);
    k_csr<<<NBUCK, 256, 0, stream>>>(binned, bucketOff, csr, offsets, dinv);

    k_prepW<<<64, 256, 0, stream>>>(W1, Wt1);
    k_prepW<<<64, 256, 0, stream>>>(W2, Wt2);

    // layer 1: hs1 = dinv * (x @ W1); h2 = relu(b1 + dinv*(sum ew*hs1 + hs1))
    k_gemm_mfma<float><<<(NN + 63) / 64, 256, 0, stream>>>(x, Wt1, dinv, hs1);
    k_agg<<<(NN + 3) / 4, 256, 0, stream>>>(hs1, offsets, csr, dinv, b1, h2);
    // layer 2
    k_gemm_mfma<unsigned short><<<(NN + 63) / 64, 256, 0, stream>>>(h2, Wt2, dinv, hs1);
    k_agg<<<(NN + 3) / 4, 256, 0, stream>>>(hs1, offsets, csr, dinv, b2, h3);
    // pool + FC
    k_pool<<<NG, 256, 0, stream>>>(h3, batch, pooled);
    k_fc<<<NG, 64, 0, stream>>>(pooled, Wfc, bfc, out);
}